// Round 5
// baseline (256.355 us; speedup 1.0000x reference)
//
#include <hip/hip_runtime.h>
#include <math.h>

#define BB 2
#define LL 1024
#define CCH 512
#define HH 8
#define LN_EPSF 1e-5f

typedef short s16x8 __attribute__((ext_vector_type(8)));
typedef float fx4 __attribute__((ext_vector_type(4)));

__device__ __forceinline__ unsigned short f2bf(float f) {
  unsigned u = __float_as_uint(f);
  unsigned r = (u + 0x7FFFu + ((u >> 16) & 1u)) >> 16;
  return (unsigned short)r;
}
__device__ __forceinline__ float bf2f(unsigned short h) {
  return __uint_as_float(((unsigned)h) << 16);
}
__device__ __forceinline__ s16x8 ldfrag(const unsigned short* p) {
  int4 t = *(const int4*)p;
  return *(s16x8*)&t;
}

// ---- DPP row_ror reductions over 16-lane rows ----
template <int CTRL>
__device__ __forceinline__ float dpp_mov(float x) {
  return __int_as_float(
      __builtin_amdgcn_update_dpp(0, __float_as_int(x), CTRL, 0xF, 0xF, true));
}
__device__ __forceinline__ float red16_sum(float v) {
  v += dpp_mov<0x121>(v);
  v += dpp_mov<0x122>(v);
  v += dpp_mov<0x124>(v);
  v += dpp_mov<0x128>(v);
  return v;
}
__device__ __forceinline__ float red16_max(float v) {
  v = fmaxf(v, dpp_mov<0x121>(v));
  v = fmaxf(v, dpp_mov<0x122>(v));
  v = fmaxf(v, dpp_mov<0x124>(v));
  v = fmaxf(v, dpp_mov<0x128>(v));
  return v;
}
__device__ __forceinline__ float wave_sum(float v) {
  v = red16_sum(v);
  v += __shfl_xor(v, 16);
  v += __shfl_xor(v, 32);
  return v;
}

// ---------------- LayerNorm -> split bf16 hi/lo ----------------
__global__ __launch_bounds__(256) void ln_split(const float* __restrict__ f,
                                                const float* __restrict__ g,
                                                const float* __restrict__ bta,
                                                unsigned short* __restrict__ xh,
                                                unsigned short* __restrict__ xl) {
  const int row = blockIdx.x;
  const int tid = threadIdx.x;
  const int wave = tid >> 6, lane = tid & 63;
  __shared__ float red[8];
  const float* fr = f + (size_t)row * CCH;
  float2 v = *(const float2*)&fr[tid * 2];
  float s = wave_sum(v.x + v.y);
  if (lane == 0) red[wave] = s;
  __syncthreads();
  float mu = (red[0] + red[1] + red[2] + red[3]) * (1.0f / CCH);
  float dx = v.x - mu, dy = v.y - mu;
  float sq = wave_sum(dx * dx + dy * dy);
  if (lane == 0) red[4 + wave] = sq;
  __syncthreads();
  float var = (red[4] + red[5] + red[6] + red[7]) * (1.0f / CCH);
  float inv = 1.0f / sqrtf(var + LN_EPSF);
  float2 gg = *(const float2*)&g[tid * 2];
  float2 bb = *(const float2*)&bta[tid * 2];
  float ox = dx * inv * gg.x + bb.x;
  float oy = dy * inv * gg.y + bb.y;
  unsigned short h0 = f2bf(ox), h1 = f2bf(oy);
  ushort2 hv; hv.x = h0; hv.y = h1;
  ushort2 lv; lv.x = f2bf(ox - bf2f(h0)); lv.y = f2bf(oy - bf2f(h1));
  *(ushort2*)&xh[(size_t)row * CCH + tid * 2] = hv;
  *(ushort2*)&xl[(size_t)row * CCH + tid * 2] = lv;
}

// ---------------- Weight pack: W[k][n] fp32 -> Wt_hi/lo[n][k] bf16 ----------------
__global__ __launch_bounds__(256) void pack_w(
    const float* __restrict__ wq, const float* __restrict__ wk,
    const float* __restrict__ wv, const float* __restrict__ wo,
    const float* __restrict__ wqp, const float* __restrict__ wkp,
    unsigned short* __restrict__ wt_h, unsigned short* __restrict__ wt_l) {
  __shared__ unsigned short lh[64][65];
  __shared__ unsigned short ll_[64][65];
  const int bx = blockIdx.x;
  const float* W;
  int Ncols, rowbase, kt, nt;
  if (bx < 256) {
    int mat = bx >> 6, t = bx & 63;
    kt = t >> 3; nt = t & 7; Ncols = 512;
    if (mat == 0) { W = wq; rowbase = 0; }
    else if (mat == 1) { W = wk; rowbase = 512; }
    else if (mat == 2) { W = wv; rowbase = 1024; }
    else { W = wo; rowbase = 1536; }
  } else {
    int r = bx - 256; int mat = r >> 4; int t = r & 15;
    kt = t >> 1; nt = t & 1; Ncols = 96;
    if (mat == 0) { W = wqp; rowbase = 2048; }
    else { W = wkp; rowbase = 2144; }
  }
  const int tid = threadIdx.x;
  const int k0 = kt * 64, n0 = nt * 64;
  const int c = tid & 63;
#pragma unroll
  for (int ii = 0; ii < 16; ++ii) {
    int r = ii * 4 + (tid >> 6);
    float val = (n0 + c < Ncols) ? W[(size_t)(k0 + r) * Ncols + n0 + c] : 0.f;
    unsigned short h = f2bf(val);
    lh[r][c] = h;
    ll_[r][c] = f2bf(val - bf2f(h));
  }
  __syncthreads();
  const int n = tid >> 2, kq = tid & 3;
  if (n0 + n < Ncols) {
    unsigned short th[16] __attribute__((aligned(16)));
    unsigned short tl[16] __attribute__((aligned(16)));
#pragma unroll
    for (int kk = 0; kk < 16; ++kk) {
      th[kk] = lh[kq * 16 + kk][n];
      tl[kk] = ll_[kq * 16 + kk][n];
    }
    unsigned short* dh = &wt_h[(size_t)(rowbase + n0 + n) * 512 + k0 + kq * 16];
    unsigned short* dl = &wt_l[(size_t)(rowbase + n0 + n) * 512 + k0 + kq * 16];
    *(int4*)dh = *(int4*)&th[0];
    *(int4*)(dh + 8) = *(int4*)&th[8];
    *(int4*)dl = *(int4*)&tl[0];
    *(int4*)(dl + 8) = *(int4*)&tl[8];
  }
}

// ---------------- Split-bf16 MFMA core, 16-row wave tile, software-pipelined ----------------
// acc[NF] over cols nw..nw+NF*16, rows mw..mw+16, K=512. Next-k fragments are
// prefetched into a second register set while current MFMAs issue.
template <int NF>
__device__ __forceinline__ void mfma_acc16(
    const unsigned short* __restrict__ Ah, const unsigned short* __restrict__ Al,
    const unsigned short* __restrict__ Bth, const unsigned short* __restrict__ Btl,
    int mw, int nw, int Nrows, fx4 acc[NF]) {
  const int lane = threadIdx.x & 63;
  const int quad = lane >> 4, l16 = lane & 15;
#pragma unroll
  for (int j = 0; j < NF; ++j) acc[j] = (fx4){0.f, 0.f, 0.f, 0.f};
  size_t aoff = (size_t)(mw + l16) * 512 + quad * 8;
  size_t boff[NF];
#pragma unroll
  for (int j = 0; j < NF; ++j) {
    int n = nw + j * 16 + l16;
    if (n > Nrows - 1) n = Nrows - 1;
    boff[j] = (size_t)n * 512 + quad * 8;
  }
  s16x8 cah = ldfrag(&Ah[aoff]), cal = ldfrag(&Al[aoff]);
  s16x8 cbh[NF], cbl[NF];
#pragma unroll
  for (int j = 0; j < NF; ++j) {
    cbh[j] = ldfrag(&Bth[boff[j]]);
    cbl[j] = ldfrag(&Btl[boff[j]]);
  }
#pragma unroll
  for (int ks = 0; ks < 16; ++ks) {
    s16x8 nah, nal, nbh[NF], nbl[NF];
    if (ks < 15) {
      size_t a2 = aoff + (size_t)(ks + 1) * 32;
      nah = ldfrag(&Ah[a2]);
      nal = ldfrag(&Al[a2]);
#pragma unroll
      for (int j = 0; j < NF; ++j) {
        nbh[j] = ldfrag(&Bth[boff[j] + (size_t)(ks + 1) * 32]);
        nbl[j] = ldfrag(&Btl[boff[j] + (size_t)(ks + 1) * 32]);
      }
    }
#pragma unroll
    for (int j = 0; j < NF; ++j) {
      acc[j] = __builtin_amdgcn_mfma_f32_16x16x32_bf16(cah, cbh[j], acc[j], 0, 0, 0);
      acc[j] = __builtin_amdgcn_mfma_f32_16x16x32_bf16(cah, cbl[j], acc[j], 0, 0, 0);
      acc[j] = __builtin_amdgcn_mfma_f32_16x16x32_bf16(cal, cbh[j], acc[j], 0, 0, 0);
    }
    if (ks < 15) {
      cah = nah; cal = nal;
#pragma unroll
      for (int j = 0; j < NF; ++j) { cbh[j] = nbh[j]; cbl[j] = nbl[j]; }
    }
  }
}

// Fused projections writing PACKED outputs. grid (14, 64), block tile 32 x 128.
__global__ __launch_bounds__(256, 4) void proj_mfma(
    const unsigned short* __restrict__ xh, const unsigned short* __restrict__ xl,
    const unsigned short* __restrict__ wt_h, const unsigned short* __restrict__ wt_l,
    const float* __restrict__ bq, const float* __restrict__ bk,
    const float* __restrict__ bv, const float* __restrict__ bqp,
    const float* __restrict__ bkp, const float* __restrict__ pscale,
    unsigned short* __restrict__ qt, unsigned short* __restrict__ kt_,
    float* __restrict__ vsb) {
  const int bx = blockIdx.x;
  const int m0 = blockIdx.y * 32;
  const float* bias;
  size_t rb; int nb, Nrows, mode;  // 0=scalar pack, 1=v fp32, 2=point pack
  unsigned short* pdst = qt;
  if (bx < 4) { rb = 0; bias = bq; nb = bx * 128; Nrows = 512; mode = 0; pdst = qt; }
  else if (bx < 8) { rb = 512; bias = bk; nb = (bx - 4) * 128; Nrows = 512; mode = 0; pdst = kt_; }
  else if (bx < 12) { rb = 1024; bias = bv; nb = (bx - 8) * 128; Nrows = 512; mode = 1; }
  else if (bx == 12) { rb = 2048; bias = bqp; nb = 0; Nrows = 96; mode = 2; pdst = qt; }
  else { rb = 2144; bias = bkp; nb = 0; Nrows = 96; mode = 2; pdst = kt_; }

  const int tid = threadIdx.x;
  const int wave = __builtin_amdgcn_readfirstlane(tid >> 6);
  const int lane = tid & 63;
  const int quad = lane >> 4, l16 = lane & 15;
  const int mw = m0 + (wave & 1) * 16;
  const int nw = nb + (wave >> 1) * 64;

  fx4 acc[4];
  mfma_acc16<4>(xh, xl, wt_h + rb * 512, wt_l + rb * 512, mw, nw, Nrows, acc);

  if (mode == 1) {
#pragma unroll
    for (int j = 0; j < 4; ++j) {
      int n = nw + j * 16 + l16;
      float bb = bias[n];
#pragma unroll
      for (int reg = 0; reg < 4; ++reg) {
        int row = mw + quad * 4 + reg;
        vsb[(size_t)row * 512 + n] = acc[j][reg] + bb;
      }
    }
  } else if (mode == 0) {
#pragma unroll
    for (int j = 0; j < 4; ++j) {
      int n = nw + j * 16 + l16;
      int h = n >> 6, d = n & 63;
      float bb = bias[n];
#pragma unroll
      for (int reg = 0; reg < 4; ++reg) {
        int row = mw + quad * 4 + reg;
        int bi = row >> 10, l = row & 1023;
        float val = (acc[j][reg] + bb) * 0.35355339059f;  // 1/sqrt(8)
        pdst[((size_t)((bi * 8 + h) * 1024 + l)) * 96 + d] = f2bf(val);
      }
    }
  } else {
#pragma unroll
    for (int j = 0; j < 4; ++j) {
      int n = nw + j * 16 + l16;
      bool ok = n < 96;
      int nn = ok ? n : 0;
      int h = nn / 12, c = nn - h * 12;
      float sc = sqrtf(2.f * pscale[h]);
      float bb = bias[nn];
#pragma unroll
      for (int reg = 0; reg < 4; ++reg) {
        int row = mw + quad * 4 + reg;
        int bi = row >> 10, l = row & 1023;
        float val = (acc[j][reg] + bb) * sc;
        if (ok)
          pdst[((size_t)((bi * 8 + h) * 1024 + l)) * 96 + 64 + c] = f2bf(val);
      }
    }
  }
}

// Output projection, block tile 32 x 64. grid (8, 64).
__global__ __launch_bounds__(256, 4) void out_proj_mfma(
    const unsigned short* __restrict__ oh, const unsigned short* __restrict__ ol,
    const unsigned short* __restrict__ wt_h, const unsigned short* __restrict__ wt_l,
    const float* __restrict__ bo, float* __restrict__ out) {
  const int tid = threadIdx.x;
  const int wave = __builtin_amdgcn_readfirstlane(tid >> 6);
  const int lane = tid & 63;
  const int quad = lane >> 4, l16 = lane & 15;
  const int mw = blockIdx.y * 32 + (wave & 1) * 16;
  const int nw = blockIdx.x * 64 + (wave >> 1) * 32;
  fx4 acc[2];
  mfma_acc16<2>(oh, ol, wt_h + (size_t)1536 * 512, wt_l + (size_t)1536 * 512, mw, nw,
                512, acc);
#pragma unroll
  for (int j = 0; j < 2; ++j) {
    int n = nw + j * 16 + l16;
    float bb = bo[n];
#pragma unroll
    for (int reg = 0; reg < 4; ++reg) {
      int row = mw + quad * 4 + reg;
      out[(size_t)row * 512 + n] = acc[j][reg] + bb;
    }
  }
}

// ---------------- sq sums from packed Q~/K~ ----------------
__global__ __launch_bounds__(256) void pack_sq(const unsigned short* __restrict__ qt,
                                               const unsigned short* __restrict__ kt_,
                                               float* __restrict__ qsqs,
                                               float* __restrict__ ksqs) {
  const int idx = blockIdx.x * 256 + threadIdx.x;
  {
    const int4* p = (const int4*)&qt[(size_t)idx * 96 + 64];
    float s = 0.f;
#pragma unroll
    for (int u = 0; u < 4; ++u) {
      int4 t = p[u];
      int w[4] = {t.x, t.y, t.z, t.w};
#pragma unroll
      for (int q = 0; q < 4; ++q) {
        float a = __uint_as_float(((unsigned)w[q]) << 16);
        float b2 = __uint_as_float(((unsigned)w[q]) & 0xFFFF0000u);
        s += a * a + b2 * b2;
      }
    }
    qsqs[idx] = 0.5f * s;
  }
  {
    const int4* p = (const int4*)&kt_[(size_t)idx * 96 + 64];
    float s = 0.f;
#pragma unroll
    for (int u = 0; u < 4; ++u) {
      int4 t = p[u];
      int w[4] = {t.x, t.y, t.z, t.w};
#pragma unroll
      for (int q = 0; q < 4; ++q) {
        float a = __uint_as_float(((unsigned)w[q]) << 16);
        float b2 = __uint_as_float(((unsigned)w[q]) & 0xFFFF0000u);
        s += a * a + b2 * b2;
      }
    }
    ksqs[idx] = 0.5f * s;
  }
}

// ---------------- Pack V: vsb fp32 -> Vt_hi/lo[bh][d][l] bf16 ----------------
__global__ __launch_bounds__(256) void pack_v(const float* __restrict__ vsb,
                                              unsigned short* __restrict__ vth,
                                              unsigned short* __restrict__ vtl) {
  __shared__ float ld[64][65];
  const int bz = blockIdx.x;
  const int bh = bz >> 4, lt = bz & 15;
  const int b = bh >> 3, h = bh & 7;
  const int l0 = lt * 64;
  const int tid = threadIdx.x;
  const int c = tid & 63;
#pragma unroll
  for (int ii = 0; ii < 16; ++ii) {
    int r = ii * 4 + (tid >> 6);
    ld[r][c] = vsb[(size_t)(b * LL + l0 + r) * CCH + h * 64 + c];
  }
  __syncthreads();
  const int d = tid >> 2, lq = tid & 3;
  unsigned short th[16] __attribute__((aligned(16)));
  unsigned short tl[16] __attribute__((aligned(16)));
#pragma unroll
  for (int kk = 0; kk < 16; ++kk) {
    float v = ld[lq * 16 + kk][d];
    unsigned short hh = f2bf(v);
    th[kk] = hh;
    tl[kk] = f2bf(v - bf2f(hh));
  }
  unsigned short* dh = &vth[((size_t)(bh * 64 + d)) * LL + l0 + lq * 16];
  unsigned short* dl = &vtl[((size_t)(bh * 64 + d)) * LL + l0 + lq * 16];
  *(int4*)dh = *(int4*)&th[0];
  *(int4*)(dh + 8) = *(int4*)&th[8];
  *(int4*)dl = *(int4*)&tl[0];
  *(int4*)(dl + 8) = *(int4*)&tl[8];
}

// ---------------- Flash IPA attention, K-split x2 across blocks ----------------
// grid (32 qtiles of 32 rows, 16 bh, 2 ksplit). Block = 4 waves =
// 2 mstrips x 2 khalves; each block covers 512 keys (8 tiles of 64).
// Emits unnormalized partials (po, pm, pl); merge_attn combines.
__global__ __launch_bounds__(256, 4) void ipa_attn_mfma(
    const unsigned short* __restrict__ qt, const unsigned short* __restrict__ kt_,
    const float* __restrict__ qsqs, const float* __restrict__ ksqs,
    const unsigned short* __restrict__ vth, const unsigned short* __restrict__ vtl,
    float* __restrict__ po, float* __restrict__ pm, float* __restrict__ pl) {
  const int qtile = blockIdx.x;
  const int bh = blockIdx.y;
  const int ksz = blockIdx.z;
  const int tid = threadIdx.x;
  const int wave = tid >> 6, lane = tid & 63;
  const int quad = lane >> 4, l16 = lane & 15;
  const int mstrip = wave & 1, khalf = wave >> 1;
  const int ibase = qtile * 32 + mstrip * 16;

  __shared__ unsigned short pb[4][16][32];
  __shared__ float obuf[4][16][64];
  __shared__ float mred[4][16], lred[4][16];

  s16x8 aq[3];
#pragma unroll
  for (int s = 0; s < 3; ++s)
    aq[s] = ldfrag(&qt[(size_t)(bh * LL + ibase + l16) * 96 + s * 32 + quad * 8]);
  float qs_r[4];
#pragma unroll
  for (int reg = 0; reg < 4; ++reg)
    qs_r[reg] = qsqs[bh * LL + ibase + quad * 4 + reg];

  fx4 o[4];
#pragma unroll
  for (int f = 0; f < 4; ++f) o[f] = (fx4){0.f, 0.f, 0.f, 0.f};
  float m_r[4], l_r[4];
#pragma unroll
  for (int reg = 0; reg < 4; ++reg) { m_r[reg] = -INFINITY; l_r[reg] = 0.f; }

  for (int kt2 = ksz * 8; kt2 < ksz * 8 + 8; ++kt2) {
    const int j0 = kt2 * 64 + khalf * 32;
    s16x8 bk[2][3];
#pragma unroll
    for (int f = 0; f < 2; ++f)
#pragma unroll
      for (int s = 0; s < 3; ++s)
        bk[f][s] = ldfrag(&kt_[(size_t)(bh * LL + j0 + f * 16 + l16) * 96 + s * 32 + quad * 8]);
    s16x8 bvh[4], bvl[4];
#pragma unroll
    for (int f = 0; f < 4; ++f) {
      size_t voff = ((size_t)(bh * 64 + f * 16 + l16)) * LL + j0 + quad * 8;
      bvh[f] = ldfrag(&vth[voff]);
      bvl[f] = ldfrag(&vtl[voff]);
    }
    float ks0 = ksqs[bh * LL + j0 + l16];
    float ks1 = ksqs[bh * LL + j0 + 16 + l16];

    fx4 sa[2];
    sa[0] = (fx4){0.f, 0.f, 0.f, 0.f};
    sa[1] = (fx4){0.f, 0.f, 0.f, 0.f};
#pragma unroll
    for (int f = 0; f < 2; ++f)
#pragma unroll
      for (int s = 0; s < 3; ++s)
        sa[f] = __builtin_amdgcn_mfma_f32_16x16x32_bf16(aq[s], bk[f][s], sa[f], 0, 0, 0);

#pragma unroll
    for (int reg = 0; reg < 4; ++reg) {
      float z0 = sa[0][reg] - qs_r[reg] - ks0;
      float z1 = sa[1][reg] - qs_r[reg] - ks1;
      float mx = red16_max(fmaxf(z0, z1));
      float mnew = fmaxf(m_r[reg], mx);
      float p0 = __expf(z0 - mnew), p1 = __expf(z1 - mnew);
      float alpha = __expf(m_r[reg] - mnew);
      float psum = red16_sum(p0 + p1);
      l_r[reg] = l_r[reg] * alpha + psum;
      m_r[reg] = mnew;
      o[0][reg] *= alpha; o[1][reg] *= alpha; o[2][reg] *= alpha; o[3][reg] *= alpha;
      pb[wave][quad * 4 + reg][l16] = f2bf(p0);
      pb[wave][quad * 4 + reg][16 + l16] = f2bf(p1);
    }
    s16x8 ap = ldfrag(&pb[wave][l16][quad * 8]);
#pragma unroll
    for (int f = 0; f < 4; ++f) {
      o[f] = __builtin_amdgcn_mfma_f32_16x16x32_bf16(ap, bvh[f], o[f], 0, 0, 0);
      o[f] = __builtin_amdgcn_mfma_f32_16x16x32_bf16(ap, bvl[f], o[f], 0, 0, 0);
    }
  }
  if (l16 == 0) {
#pragma unroll
    for (int reg = 0; reg < 4; ++reg) {
      mred[wave][quad * 4 + reg] = m_r[reg];
      lred[wave][quad * 4 + reg] = l_r[reg];
    }
  }
#pragma unroll
  for (int f = 0; f < 4; ++f)
#pragma unroll
    for (int reg = 0; reg < 4; ++reg)
      obuf[wave][quad * 4 + reg][f * 16 + l16] = o[f][reg];
  __syncthreads();
  if (khalf == 0) {
    const int pw = wave + 2;
    const size_t rbase = ((size_t)ksz * 16 + bh) * LL + ibase;
#pragma unroll
    for (int f = 0; f < 4; ++f)
#pragma unroll
      for (int reg = 0; reg < 4; ++reg) {
        int row = quad * 4 + reg;
        int d = f * 16 + l16;
        float m0v = mred[wave][row], m1v = mred[pw][row];
        float l0v = lred[wave][row], l1v = lred[pw][row];
        float M = fmaxf(m0v, m1v);
        float w0 = __expf(m0v - M), w1 = __expf(m1v - M);
        float Lv = l0v * w0 + l1v * w1;
        float val = obuf[wave][row][d] * w0 + obuf[pw][row][d] * w1;
        po[(rbase + row) * 64 + d] = val;
        if (f == 0 && l16 == 0) {
          pm[rbase + row] = M;
          pl[rbase + row] = Lv;
        }
      }
  }
}

// ---------------- Merge the two K-split partials -> bf16 hi/lo ----------------
__global__ __launch_bounds__(256) void merge_attn(const float* __restrict__ po,
                                                  const float* __restrict__ pm,
                                                  const float* __restrict__ pl,
                                                  unsigned short* __restrict__ oh,
                                                  unsigned short* __restrict__ ol) {
  const int r = blockIdx.x * 4 + (threadIdx.x >> 6);  // row in [0, 16*1024)
  const int lane = threadIdx.x & 63;
  const size_t half = (size_t)16 * LL;
  float m0 = pm[r], m1 = pm[half + r];
  float l0 = pl[r], l1 = pl[half + r];
  float M = fmaxf(m0, m1);
  float w0 = __expf(m0 - M), w1 = __expf(m1 - M);
  float L = l0 * w0 + l1 * w1;
  float v = (po[(size_t)r * 64 + lane] * w0 + po[(half + r) * 64 + lane] * w1) / L;
  int bh = r >> 10, l = r & 1023;
  int b = bh >> 3, h = bh & 7;
  size_t addr = ((size_t)(b * LL + l)) * CCH + h * 64 + lane;
  unsigned short hv = f2bf(v);
  oh[addr] = hv;
  ol[addr] = f2bf(v - bf2f(hv));
}

extern "C" void kernel_launch(void* const* d_in, const int* in_sizes, int n_in,
                              void* d_out, int out_size, void* d_ws, size_t ws_size,
                              hipStream_t stream) {
  (void)in_sizes; (void)n_in; (void)out_size; (void)ws_size;
  const float* features = (const float*)d_in[0];
  const float* ln_g = (const float*)d_in[2];
  const float* ln_b = (const float*)d_in[3];
  const float* wq = (const float*)d_in[4];
  const float* bq = (const float*)d_in[5];
  const float* wk = (const float*)d_in[6];
  const float* bk = (const float*)d_in[7];
  const float* wv = (const float*)d_in[8];
  const float* bv = (const float*)d_in[9];
  const float* wqp = (const float*)d_in[10];
  const float* bqp = (const float*)d_in[11];
  const float* wkp = (const float*)d_in[12];
  const float* bkp = (const float*)d_in[13];
  const float* wo = (const float*)d_in[16];
  const float* bo = (const float*)d_in[17];
  const float* pscale = (const float*)d_in[18];
  float* out = (float*)d_out;

  char* cur = (char*)d_ws;
  const size_t NTOK = (size_t)BB * LL;  // 2048
  unsigned short* xh = (unsigned short*)cur; cur += NTOK * CCH * 2;
  unsigned short* xl = (unsigned short*)cur; cur += NTOK * CCH * 2;
  unsigned short* wt_h = (unsigned short*)cur; cur += (size_t)2240 * 512 * 2;
  unsigned short* wt_l = (unsigned short*)cur; cur += (size_t)2240 * 512 * 2;
  float* vsb = (float*)cur; cur += NTOK * CCH * 4;
  unsigned short* qt = (unsigned short*)cur; cur += (size_t)16 * LL * 96 * 2;
  unsigned short* kt_ = (unsigned short*)cur; cur += (size_t)16 * LL * 96 * 2;
  float* qsqs = (float*)cur; cur += (size_t)16 * LL * 4;
  float* ksqs = (float*)cur; cur += (size_t)16 * LL * 4;
  unsigned short* vth = (unsigned short*)cur; cur += (size_t)16 * 64 * LL * 2;
  unsigned short* vtl = (unsigned short*)cur; cur += (size_t)16 * 64 * LL * 2;
  unsigned short* oh = (unsigned short*)cur; cur += NTOK * CCH * 2;
  unsigned short* ol = (unsigned short*)cur; cur += NTOK * CCH * 2;
  float* po = (float*)cur; cur += (size_t)2 * 16 * LL * 64 * 4;
  float* pm = (float*)cur; cur += (size_t)2 * 16 * LL * 4;
  float* pl = (float*)cur; cur += (size_t)2 * 16 * LL * 4;

  // zero packed Q~/K~ (covers K=96 pad cols 76..95); qt,kt adjacent
  hipMemsetAsync(qt, 0, (size_t)2 * 16 * LL * 96 * 2, stream);

  ln_split<<<dim3((unsigned)NTOK), 256, 0, stream>>>(features, ln_g, ln_b, xh, xl);
  pack_w<<<dim3(288), 256, 0, stream>>>(wq, wk, wv, wo, wqp, wkp, wt_h, wt_l);
  proj_mfma<<<dim3(14, 64), 256, 0, stream>>>(xh, xl, wt_h, wt_l, bq, bk, bv, bqp,
                                              bkp, pscale, qt, kt_, vsb);
  pack_sq<<<dim3(128), 256, 0, stream>>>(qt, kt_, qsqs, ksqs);
  pack_v<<<dim3(256), 256, 0, stream>>>(vsb, vth, vtl);
  ipa_attn_mfma<<<dim3(32, 16, 2), 256, 0, stream>>>(qt, kt_, qsqs, ksqs, vth, vtl,
                                                     po, pm, pl);
  merge_attn<<<dim3(4096), 256, 0, stream>>>(po, pm, pl, oh, ol);
  out_proj_mfma<<<dim3(8, 64), 256, 0, stream>>>(oh, ol, wt_h, wt_l, bo, out);
}

// Round 6
// 200.243 us; speedup vs baseline: 1.2802x; 1.2802x over previous
//
#include <hip/hip_runtime.h>
#include <math.h>

#define BB 2
#define LL 1024
#define CCH 512
#define HH 8
#define LN_EPSF 1e-5f

typedef short s16x8 __attribute__((ext_vector_type(8)));
typedef float fx4 __attribute__((ext_vector_type(4)));

__device__ __forceinline__ unsigned short f2bf(float f) {
  unsigned u = __float_as_uint(f);
  unsigned r = (u + 0x7FFFu + ((u >> 16) & 1u)) >> 16;
  return (unsigned short)r;
}
__device__ __forceinline__ float bf2f(unsigned short h) {
  return __uint_as_float(((unsigned)h) << 16);
}
__device__ __forceinline__ s16x8 ldfrag(const unsigned short* p) {
  int4 t = *(const int4*)p;
  return *(s16x8*)&t;
}

// ---- DPP row_ror reductions over 16-lane rows ----
template <int CTRL>
__device__ __forceinline__ float dpp_mov(float x) {
  return __int_as_float(
      __builtin_amdgcn_update_dpp(0, __float_as_int(x), CTRL, 0xF, 0xF, true));
}
__device__ __forceinline__ float red16_sum(float v) {
  v += dpp_mov<0x121>(v);
  v += dpp_mov<0x122>(v);
  v += dpp_mov<0x124>(v);
  v += dpp_mov<0x128>(v);
  return v;
}
__device__ __forceinline__ float red16_max(float v) {
  v = fmaxf(v, dpp_mov<0x121>(v));
  v = fmaxf(v, dpp_mov<0x122>(v));
  v = fmaxf(v, dpp_mov<0x124>(v));
  v = fmaxf(v, dpp_mov<0x128>(v));
  return v;
}
__device__ __forceinline__ float wave_sum(float v) {
  v = red16_sum(v);
  v += __shfl_xor(v, 16);
  v += __shfl_xor(v, 32);
  return v;
}

// ---------------- LayerNorm -> split bf16 hi/lo ----------------
__global__ __launch_bounds__(256) void ln_split(const float* __restrict__ f,
                                                const float* __restrict__ g,
                                                const float* __restrict__ bta,
                                                unsigned short* __restrict__ xh,
                                                unsigned short* __restrict__ xl) {
  const int row = blockIdx.x;
  const int tid = threadIdx.x;
  const int wave = tid >> 6, lane = tid & 63;
  __shared__ float red[8];
  const float* fr = f + (size_t)row * CCH;
  float2 v = *(const float2*)&fr[tid * 2];
  float s = wave_sum(v.x + v.y);
  if (lane == 0) red[wave] = s;
  __syncthreads();
  float mu = (red[0] + red[1] + red[2] + red[3]) * (1.0f / CCH);
  float dx = v.x - mu, dy = v.y - mu;
  float sq = wave_sum(dx * dx + dy * dy);
  if (lane == 0) red[4 + wave] = sq;
  __syncthreads();
  float var = (red[4] + red[5] + red[6] + red[7]) * (1.0f / CCH);
  float inv = 1.0f / sqrtf(var + LN_EPSF);
  float2 gg = *(const float2*)&g[tid * 2];
  float2 bb = *(const float2*)&bta[tid * 2];
  float ox = dx * inv * gg.x + bb.x;
  float oy = dy * inv * gg.y + bb.y;
  unsigned short h0 = f2bf(ox), h1 = f2bf(oy);
  ushort2 hv; hv.x = h0; hv.y = h1;
  ushort2 lv; lv.x = f2bf(ox - bf2f(h0)); lv.y = f2bf(oy - bf2f(h1));
  *(ushort2*)&xh[(size_t)row * CCH + tid * 2] = hv;
  *(ushort2*)&xl[(size_t)row * CCH + tid * 2] = lv;
}

// ---------------- Weight pack: W[k][n] fp32 -> Wt[n][k] bf16 (hi only) ----------------
// wt row map: q:0, k:512, v:1024, o:1536, qp:2048(+96), kp:2144(+96)
__global__ __launch_bounds__(256) void pack_w(
    const float* __restrict__ wq, const float* __restrict__ wk,
    const float* __restrict__ wv, const float* __restrict__ wo,
    const float* __restrict__ wqp, const float* __restrict__ wkp,
    unsigned short* __restrict__ wt_h) {
  __shared__ unsigned short lh[64][68];
  const int bx = blockIdx.x;
  const float* W;
  int Ncols, rowbase, kt, nt;
  if (bx < 256) {
    int mat = bx >> 6, t = bx & 63;
    kt = t >> 3; nt = t & 7; Ncols = 512;
    if (mat == 0) { W = wq; rowbase = 0; }
    else if (mat == 1) { W = wk; rowbase = 512; }
    else if (mat == 2) { W = wv; rowbase = 1024; }
    else { W = wo; rowbase = 1536; }
  } else {
    int r = bx - 256; int mat = r >> 4; int t = r & 15;
    kt = t >> 1; nt = t & 1; Ncols = 96;
    if (mat == 0) { W = wqp; rowbase = 2048; }
    else { W = wkp; rowbase = 2144; }
  }
  const int tid = threadIdx.x;
  const int k0 = kt * 64, n0 = nt * 64;
  const int c = tid & 63;
#pragma unroll
  for (int ii = 0; ii < 16; ++ii) {
    int r = ii * 4 + (tid >> 6);
    float val = (n0 + c < Ncols) ? W[(size_t)(k0 + r) * Ncols + n0 + c] : 0.f;
    lh[r][c] = f2bf(val);
  }
  __syncthreads();
  const int n = tid >> 2, kq = tid & 3;
  if (n0 + n < Ncols) {
    unsigned short th[16] __attribute__((aligned(16)));
#pragma unroll
    for (int kk = 0; kk < 16; ++kk) th[kk] = lh[kq * 16 + kk][n];
    unsigned short* dh = &wt_h[(size_t)(rowbase + n0 + n) * 512 + k0 + kq * 16];
    *(int4*)dh = *(int4*)&th[0];
    *(int4*)(dh + 8) = *(int4*)&th[8];
  }
}

// ---------------- MFMA core: acc[MF][NF] over rows mw.., cols nw.. ----------------
// TERMS=1: Ah@B.  TERMS=2: Ah@B + Al@B (split-A, single-B).
template <int MF, int NF, int TERMS>
__device__ __forceinline__ void mfma_core(
    const unsigned short* __restrict__ Ah, const unsigned short* __restrict__ Al,
    const unsigned short* __restrict__ Bt, int mw, int nw, int Nrows,
    int ks0, int ks1, fx4 acc[MF][NF]) {
  const int lane = threadIdx.x & 63;
  const int quad = lane >> 4, l16 = lane & 15;
#pragma unroll
  for (int i = 0; i < MF; ++i)
#pragma unroll
    for (int j = 0; j < NF; ++j) acc[i][j] = (fx4){0.f, 0.f, 0.f, 0.f};
  size_t boff[NF];
#pragma unroll
  for (int j = 0; j < NF; ++j) {
    int n = nw + j * 16 + l16;
    if (n > Nrows - 1) n = Nrows - 1;
    boff[j] = (size_t)n * 512 + quad * 8;
  }
  for (int ks = ks0; ks < ks1; ++ks) {
    const int k = ks * 32 + quad * 8;
    s16x8 ah[MF], al[MF], b[NF];
#pragma unroll
    for (int i = 0; i < MF; ++i) {
      size_t off = (size_t)(mw + i * 16 + l16) * 512 + k;
      ah[i] = ldfrag(&Ah[off]);
      if (TERMS == 2) al[i] = ldfrag(&Al[off]);
    }
#pragma unroll
    for (int j = 0; j < NF; ++j) b[j] = ldfrag(&Bt[boff[j] + (size_t)ks * 32]);
#pragma unroll
    for (int i = 0; i < MF; ++i)
#pragma unroll
      for (int j = 0; j < NF; ++j) {
        acc[i][j] = __builtin_amdgcn_mfma_f32_16x16x32_bf16(ah[i], b[j], acc[i][j], 0, 0, 0);
        if (TERMS == 2)
          acc[i][j] = __builtin_amdgcn_mfma_f32_16x16x32_bf16(al[i], b[j], acc[i][j], 0, 0, 0);
      }
  }
}

// ---------------- Fused projections -> packed outputs. grid (18, 32) ----------------
// bx 0..3: q (bf16 pack, hi-only A), 4..7: k, 8..15: v (64-wide tiles, split-A),
// 16: qp, 17: kp. Block rows = by*64 .. +64.
__global__ __launch_bounds__(256, 4) void proj_mfma(
    const unsigned short* __restrict__ xh, const unsigned short* __restrict__ xl,
    const unsigned short* __restrict__ wt_h,
    const float* __restrict__ bq, const float* __restrict__ bk,
    const float* __restrict__ bv, const float* __restrict__ bqp,
    const float* __restrict__ bkp, const float* __restrict__ pscale,
    unsigned short* __restrict__ qt, unsigned short* __restrict__ kt_,
    unsigned short* __restrict__ vh) {
  const int bx = blockIdx.x;
  const int m0 = blockIdx.y * 64;
  const int tid = threadIdx.x;
  const int wave = __builtin_amdgcn_readfirstlane(tid >> 6);
  const int lane = tid & 63;
  const int quad = lane >> 4, l16 = lane & 15;
  const int mw = m0 + (wave & 1) * 32;

  if (bx < 8) {  // q or k scalar: hi-only, NF=4
    const bool isq = bx < 4;
    const float* bias = isq ? bq : bk;
    unsigned short* pdst = isq ? qt : kt_;
    const int nb = (bx & 3) * 128;
    const int nw = nb + (wave >> 1) * 64;
    fx4 acc[2][4];
    mfma_core<2, 4, 1>(xh, xh, wt_h + (isq ? 0 : (size_t)512 * 512), mw, nw, 512,
                       0, 16, acc);
#pragma unroll
    for (int j = 0; j < 4; ++j) {
      int n = nw + j * 16 + l16;
      int h = n >> 6, d = n & 63;
      float bb = bias[n];
#pragma unroll
      for (int i = 0; i < 2; ++i)
#pragma unroll
        for (int reg = 0; reg < 4; ++reg) {
          int row = mw + i * 16 + quad * 4 + reg;
          int bi = row >> 10, l = row & 1023;
          float val = (acc[i][j][reg] + bb) * 0.35355339059f;  // 1/sqrt(8)
          pdst[((size_t)((bi * 8 + h) * 1024 + l)) * 96 + d] = f2bf(val);
        }
    }
  } else if (bx < 16) {  // v: split-A, NF=2 (64-wide tiles)
    const int nb = (bx - 8) * 64;
    const int nw = nb + (wave >> 1) * 32;
    fx4 acc[2][2];
    mfma_core<2, 2, 2>(xh, xl, wt_h + (size_t)1024 * 512, mw, nw, 512, 0, 16, acc);
#pragma unroll
    for (int j = 0; j < 2; ++j) {
      int n = nw + j * 16 + l16;
      float bb = bv[n];
#pragma unroll
      for (int i = 0; i < 2; ++i)
#pragma unroll
        for (int reg = 0; reg < 4; ++reg) {
          int row = mw + i * 16 + quad * 4 + reg;
          vh[(size_t)row * 512 + n] = f2bf(acc[i][j][reg] + bb);
        }
    }
  } else {  // qp / kp point: hi-only, NF=4, cols 0..95
    const bool isq = bx == 16;
    const float* bias = isq ? bqp : bkp;
    unsigned short* pdst = isq ? qt : kt_;
    const int nw = (wave >> 1) * 64;
    fx4 acc[2][4];
    mfma_core<2, 4, 1>(xh, xh, wt_h + (isq ? (size_t)2048 : (size_t)2144) * 512,
                       mw, nw, 96, 0, 16, acc);
#pragma unroll
    for (int j = 0; j < 4; ++j) {
      int n = nw + j * 16 + l16;
      bool ok = n < 96;
      int nn = ok ? n : 0;
      int h = nn / 12, c = nn - h * 12;
      float sc = sqrtf(2.f * pscale[h]);
      float bb = bias[nn];
#pragma unroll
      for (int i = 0; i < 2; ++i)
#pragma unroll
        for (int reg = 0; reg < 4; ++reg) {
          int row = mw + i * 16 + quad * 4 + reg;
          int bi = row >> 10, l = row & 1023;
          float val = (acc[i][j][reg] + bb) * sc;
          if (ok)
            pdst[((size_t)((bi * 8 + h) * 1024 + l)) * 96 + 64 + c] = f2bf(val);
        }
    }
  }
}

// ---------------- Output projection: split-A, K-split x2, atomic accumulate ----------------
// grid (8, 32, 2): 64x64 tile, K half per z. out must be pre-zeroed.
__global__ __launch_bounds__(256, 4) void out_proj_mfma(
    const unsigned short* __restrict__ oh, const unsigned short* __restrict__ ol,
    const unsigned short* __restrict__ wt_h, const float* __restrict__ bo,
    float* __restrict__ out) {
  const int tid = threadIdx.x;
  const int wave = __builtin_amdgcn_readfirstlane(tid >> 6);
  const int lane = tid & 63;
  const int quad = lane >> 4, l16 = lane & 15;
  const int mw = blockIdx.y * 64 + (wave & 1) * 32;
  const int nw = blockIdx.x * 64 + (wave >> 1) * 32;
  const int kz = blockIdx.z;
  fx4 acc[2][2];
  mfma_core<2, 2, 2>(oh, ol, wt_h + (size_t)1536 * 512, mw, nw, 512, kz * 8,
                     kz * 8 + 8, acc);
#pragma unroll
  for (int j = 0; j < 2; ++j) {
    int n = nw + j * 16 + l16;
    float bb = (kz == 0) ? bo[n] : 0.f;
#pragma unroll
    for (int i = 0; i < 2; ++i)
#pragma unroll
      for (int reg = 0; reg < 4; ++reg) {
        int row = mw + i * 16 + quad * 4 + reg;
        atomicAdd(&out[(size_t)row * 512 + n], acc[i][j][reg] + bb);
      }
  }
}

// ---------------- sq sums from packed Q~/K~ ----------------
__global__ __launch_bounds__(256) void pack_sq(const unsigned short* __restrict__ qt,
                                               const unsigned short* __restrict__ kt_,
                                               float* __restrict__ qsqs,
                                               float* __restrict__ ksqs) {
  const int idx = blockIdx.x * 256 + threadIdx.x;  // row in [0, 16*1024)
  {
    const int4* p = (const int4*)&qt[(size_t)idx * 96 + 64];
    float s = 0.f;
#pragma unroll
    for (int u = 0; u < 4; ++u) {
      int4 t = p[u];
      int w[4] = {t.x, t.y, t.z, t.w};
#pragma unroll
      for (int q = 0; q < 4; ++q) {
        float a = __uint_as_float(((unsigned)w[q]) << 16);
        float b2 = __uint_as_float(((unsigned)w[q]) & 0xFFFF0000u);
        s += a * a + b2 * b2;
      }
    }
    qsqs[idx] = 0.5f * s;
  }
  {
    const int4* p = (const int4*)&kt_[(size_t)idx * 96 + 64];
    float s = 0.f;
#pragma unroll
    for (int u = 0; u < 4; ++u) {
      int4 t = p[u];
      int w[4] = {t.x, t.y, t.z, t.w};
#pragma unroll
      for (int q = 0; q < 4; ++q) {
        float a = __uint_as_float(((unsigned)w[q]) << 16);
        float b2 = __uint_as_float(((unsigned)w[q]) & 0xFFFF0000u);
        s += a * a + b2 * b2;
      }
    }
    ksqs[idx] = 0.5f * s;
  }
}

// ---------------- Pack V: vh bf16 [tok][512] -> Vt[bh][d][l] bf16 ----------------
__global__ __launch_bounds__(256) void pack_v(const unsigned short* __restrict__ vh,
                                              unsigned short* __restrict__ vth) {
  __shared__ unsigned short ld[64][68];
  const int bz = blockIdx.x;  // bh*16 + ltile
  const int bh = bz >> 4, lt = bz & 15;
  const int b = bh >> 3, h = bh & 7;
  const int l0 = lt * 64;
  const int tid = threadIdx.x;
  const int c = tid & 63;
#pragma unroll
  for (int ii = 0; ii < 16; ++ii) {
    int r = ii * 4 + (tid >> 6);
    ld[r][c] = vh[(size_t)(b * LL + l0 + r) * CCH + h * 64 + c];
  }
  __syncthreads();
  const int d = tid >> 2, lq = tid & 3;
  unsigned short th[16] __attribute__((aligned(16)));
#pragma unroll
  for (int kk = 0; kk < 16; ++kk) th[kk] = ld[lq * 16 + kk][d];
  unsigned short* dh = &vth[((size_t)(bh * 64 + d)) * LL + l0 + lq * 16];
  *(int4*)dh = *(int4*)&th[0];
  *(int4*)(dh + 8) = *(int4*)&th[8];
}

// ---------------- Flash IPA attention, K-split x4 across blocks ----------------
// grid (32 qtiles of 32 rows, 16 bh, 4 ksplit). Block = 4 waves =
// 2 mstrips x 2 khalves; each block covers 256 keys (4 tiles of 64).
__global__ __launch_bounds__(256, 4) void ipa_attn_mfma(
    const unsigned short* __restrict__ qt, const unsigned short* __restrict__ kt_,
    const float* __restrict__ qsqs, const float* __restrict__ ksqs,
    const unsigned short* __restrict__ vth,
    float* __restrict__ po, float* __restrict__ pm, float* __restrict__ pl) {
  const int qtile = blockIdx.x;
  const int bh = blockIdx.y;
  const int ksz = blockIdx.z;
  const int tid = threadIdx.x;
  const int wave = tid >> 6, lane = tid & 63;
  const int quad = lane >> 4, l16 = lane & 15;
  const int mstrip = wave & 1, khalf = wave >> 1;
  const int ibase = qtile * 32 + mstrip * 16;

  __shared__ unsigned short pb[4][16][32];
  __shared__ float obuf[4][16][64];
  __shared__ float mred[4][16], lred[4][16];

  s16x8 aq[3];
#pragma unroll
  for (int s = 0; s < 3; ++s)
    aq[s] = ldfrag(&qt[(size_t)(bh * LL + ibase + l16) * 96 + s * 32 + quad * 8]);
  float qs_r[4];
#pragma unroll
  for (int reg = 0; reg < 4; ++reg)
    qs_r[reg] = qsqs[bh * LL + ibase + quad * 4 + reg];

  fx4 o[4];
#pragma unroll
  for (int f = 0; f < 4; ++f) o[f] = (fx4){0.f, 0.f, 0.f, 0.f};
  float m_r[4], l_r[4];
#pragma unroll
  for (int reg = 0; reg < 4; ++reg) { m_r[reg] = -INFINITY; l_r[reg] = 0.f; }

  for (int kt2 = ksz * 4; kt2 < ksz * 4 + 4; ++kt2) {
    const int j0 = kt2 * 64 + khalf * 32;
    s16x8 bk[2][3];
#pragma unroll
    for (int f = 0; f < 2; ++f)
#pragma unroll
      for (int s = 0; s < 3; ++s)
        bk[f][s] = ldfrag(&kt_[(size_t)(bh * LL + j0 + f * 16 + l16) * 96 + s * 32 + quad * 8]);
    s16x8 bvh[4];
#pragma unroll
    for (int f = 0; f < 4; ++f)
      bvh[f] = ldfrag(&vth[((size_t)(bh * 64 + f * 16 + l16)) * LL + j0 + quad * 8]);
    float ks0 = ksqs[bh * LL + j0 + l16];
    float ks1 = ksqs[bh * LL + j0 + 16 + l16];

    fx4 sa[2];
    sa[0] = (fx4){0.f, 0.f, 0.f, 0.f};
    sa[1] = (fx4){0.f, 0.f, 0.f, 0.f};
#pragma unroll
    for (int f = 0; f < 2; ++f)
#pragma unroll
      for (int s = 0; s < 3; ++s)
        sa[f] = __builtin_amdgcn_mfma_f32_16x16x32_bf16(aq[s], bk[f][s], sa[f], 0, 0, 0);

#pragma unroll
    for (int reg = 0; reg < 4; ++reg) {
      float z0 = sa[0][reg] - qs_r[reg] - ks0;
      float z1 = sa[1][reg] - qs_r[reg] - ks1;
      float mx = red16_max(fmaxf(z0, z1));
      float mnew = fmaxf(m_r[reg], mx);
      float p0 = __expf(z0 - mnew), p1 = __expf(z1 - mnew);
      float alpha = __expf(m_r[reg] - mnew);
      float psum = red16_sum(p0 + p1);
      l_r[reg] = l_r[reg] * alpha + psum;
      m_r[reg] = mnew;
      o[0][reg] *= alpha; o[1][reg] *= alpha; o[2][reg] *= alpha; o[3][reg] *= alpha;
      pb[wave][quad * 4 + reg][l16] = f2bf(p0);
      pb[wave][quad * 4 + reg][16 + l16] = f2bf(p1);
    }
    s16x8 ap = ldfrag(&pb[wave][l16][quad * 8]);
#pragma unroll
    for (int f = 0; f < 4; ++f)
      o[f] = __builtin_amdgcn_mfma_f32_16x16x32_bf16(ap, bvh[f], o[f], 0, 0, 0);
  }
  if (l16 == 0) {
#pragma unroll
    for (int reg = 0; reg < 4; ++reg) {
      mred[wave][quad * 4 + reg] = m_r[reg];
      lred[wave][quad * 4 + reg] = l_r[reg];
    }
  }
#pragma unroll
  for (int f = 0; f < 4; ++f)
#pragma unroll
    for (int reg = 0; reg < 4; ++reg)
      obuf[wave][quad * 4 + reg][f * 16 + l16] = o[f][reg];
  __syncthreads();
  if (khalf == 0) {
    const int pw = wave + 2;
    const size_t rbase = ((size_t)ksz * 16 + bh) * LL + ibase;
#pragma unroll
    for (int f = 0; f < 4; ++f)
#pragma unroll
      for (int reg = 0; reg < 4; ++reg) {
        int row = quad * 4 + reg;
        int d = f * 16 + l16;
        float m0v = mred[wave][row], m1v = mred[pw][row];
        float l0v = lred[wave][row], l1v = lred[pw][row];
        float M = fmaxf(m0v, m1v);
        float w0 = __expf(m0v - M), w1 = __expf(m1v - M);
        float Lv = l0v * w0 + l1v * w1;
        float val = obuf[wave][row][d] * w0 + obuf[pw][row][d] * w1;
        po[(rbase + row) * 64 + d] = val;
        if (f == 0 && l16 == 0) {
          pm[rbase + row] = M;
          pl[rbase + row] = Lv;
        }
      }
  }
}

// ---------------- Merge the 4 K-split partials -> bf16 hi/lo ----------------
__global__ __launch_bounds__(256) void merge_attn(const float* __restrict__ po,
                                                  const float* __restrict__ pm,
                                                  const float* __restrict__ pl,
                                                  unsigned short* __restrict__ oh,
                                                  unsigned short* __restrict__ ol) {
  const int r = blockIdx.x * 4 + (threadIdx.x >> 6);  // row in [0, 16*1024)
  const int lane = threadIdx.x & 63;
  const size_t part = (size_t)16 * LL;
  float M = -INFINITY;
#pragma unroll
  for (int p = 0; p < 4; ++p) M = fmaxf(M, pm[p * part + r]);
  float L = 0.f, v = 0.f;
#pragma unroll
  for (int p = 0; p < 4; ++p) {
    float w = __expf(pm[p * part + r] - M);
    L += pl[p * part + r] * w;
    v += po[(p * part + r) * 64 + lane] * w;
  }
  v /= L;
  int bh = r >> 10, l = r & 1023;
  int b = bh >> 3, h = bh & 7;
  size_t addr = ((size_t)(b * LL + l)) * CCH + h * 64 + lane;
  unsigned short hv = f2bf(v);
  oh[addr] = hv;
  ol[addr] = f2bf(v - bf2f(hv));
}

extern "C" void kernel_launch(void* const* d_in, const int* in_sizes, int n_in,
                              void* d_out, int out_size, void* d_ws, size_t ws_size,
                              hipStream_t stream) {
  (void)in_sizes; (void)n_in; (void)out_size; (void)ws_size;
  const float* features = (const float*)d_in[0];
  const float* ln_g = (const float*)d_in[2];
  const float* ln_b = (const float*)d_in[3];
  const float* wq = (const float*)d_in[4];
  const float* bq = (const float*)d_in[5];
  const float* wk = (const float*)d_in[6];
  const float* bk = (const float*)d_in[7];
  const float* wv = (const float*)d_in[8];
  const float* bv = (const float*)d_in[9];
  const float* wqp = (const float*)d_in[10];
  const float* bqp = (const float*)d_in[11];
  const float* wkp = (const float*)d_in[12];
  const float* bkp = (const float*)d_in[13];
  const float* wo = (const float*)d_in[16];
  const float* bo = (const float*)d_in[17];
  const float* pscale = (const float*)d_in[18];
  float* out = (float*)d_out;

  char* cur = (char*)d_ws;
  const size_t NTOK = (size_t)BB * LL;  // 2048
  unsigned short* xh = (unsigned short*)cur; cur += NTOK * CCH * 2;
  unsigned short* xl = (unsigned short*)cur; cur += NTOK * CCH * 2;
  unsigned short* wt_h = (unsigned short*)cur; cur += (size_t)2240 * 512 * 2;
  unsigned short* vh = (unsigned short*)cur; cur += NTOK * CCH * 2;
  unsigned short* qt = (unsigned short*)cur; cur += (size_t)16 * LL * 96 * 2;
  unsigned short* kt_ = (unsigned short*)cur; cur += (size_t)16 * LL * 96 * 2;
  float* qsqs = (float*)cur; cur += (size_t)16 * LL * 4;
  float* ksqs = (float*)cur; cur += (size_t)16 * LL * 4;
  unsigned short* vth = (unsigned short*)cur; cur += (size_t)16 * 64 * LL * 2;
  unsigned short* oh = (unsigned short*)cur; cur += NTOK * CCH * 2;
  unsigned short* ol = (unsigned short*)cur; cur += NTOK * CCH * 2;
  float* po = (float*)cur; cur += (size_t)4 * 16 * LL * 64 * 4;
  float* pm = (float*)cur; cur += (size_t)4 * 16 * LL * 4;
  float* pl = (float*)cur; cur += (size_t)4 * 16 * LL * 4;

  // zero packed Q~/K~ (covers K=96 pad cols 76..95; qt,kt adjacent) and out
  hipMemsetAsync(qt, 0, (size_t)2 * 16 * LL * 96 * 2, stream);
  hipMemsetAsync(out, 0, NTOK * CCH * 4, stream);

  ln_split<<<dim3((unsigned)NTOK), 256, 0, stream>>>(features, ln_g, ln_b, xh, xl);
  pack_w<<<dim3(288), 256, 0, stream>>>(wq, wk, wv, wo, wqp, wkp, wt_h);
  proj_mfma<<<dim3(18, 32), 256, 0, stream>>>(xh, xl, wt_h, bq, bk, bv, bqp, bkp,
                                              pscale, qt, kt_, vh);
  pack_sq<<<dim3(64), 256, 0, stream>>>(qt, kt_, qsqs, ksqs);
  pack_v<<<dim3(256), 256, 0, stream>>>(vh, vth);
  ipa_attn_mfma<<<dim3(32, 16, 4), 256, 0, stream>>>(qt, kt_, qsqs, ksqs, vth,
                                                     po, pm, pl);
  merge_attn<<<dim3(4096), 256, 0, stream>>>(po, pm, pl, oh, ol);
  out_proj_mfma<<<dim3(8, 32, 2), 256, 0, stream>>>(oh, ol, wt_h, bo, out);
}